// Round 3
// baseline (578.454 us; speedup 1.0000x reference)
//
#include <hip/hip_runtime.h>

#define K_TAGS 50
#define T_MAX 256
#define START_TAG 48
#define END_TAG 49
#define LOG2E 1.4426950408889634f
#define LN2 0.6931471805599453f

// hardware transcendentals: v_exp_f32 is 2^x, v_log_f32 is log2(x)
#define EXP2F(x) __builtin_amdgcn_exp2f(x)
#define LOG2F(x) __builtin_amdgcn_logf(x)

// Raw workgroup barrier that drains ONLY the LDS counter (lgkmcnt), leaving
// global prefetch loads in flight. __syncthreads would emit
// s_waitcnt vmcnt(0) lgkmcnt(0) and kill the software pipeline.
// All cross-wave communication in this kernel goes through LDS, so
// lgkmcnt(0) + s_barrier is sufficient for correctness.
#define LDS_BARRIER() __asm__ volatile("s_waitcnt lgkmcnt(0)\n\ts_barrier" ::: "memory")

// One block per batch element. 512 threads = 8 waves.
// Lane j owns output column j; wave w owns rows i == w (mod 8).
// Scaled forward algorithm in LINEAR domain: L[j] = 2^(beta[j]-M).
//   L_new[j] = 2^-E0 * sum_i P[t][i][j] * L[i],  P = 2^(s*log2e),  M += E0
// E0 = floor-exponent of L[0] (bit extract, no transcendental on the chain).
// P for step t+1 is exp'd at step t (independent of L -> off critical path).
// Scores prefetched 4 steps deep in registers; 4 rotating csum buffers give
// one LDS-only barrier per step.
__global__ __launch_bounds__(512, 1) void crf_fwd_kernel(
    const float* __restrict__ scores, const int* __restrict__ targets,
    const int* __restrict__ lengths, float* __restrict__ accum)
{
    const int b    = blockIdx.x;
    const int tid  = threadIdx.x;
    const int wave = tid >> 6;
    const int lane = tid & 63;
    const int len  = lengths[b];
    const float* __restrict__ sp = scores + (size_t)b * T_MAX * K_TAGS * K_TAGS;

    // ---------------- gold score (threads 0..255 handle t = tid) ----------------
    if (tid < T_MAX) {
        float g = 0.f;
        if (tid < len) {
            int tg = targets[b * T_MAX + tid];
            g = sp[(size_t)tid * (K_TAGS * K_TAGS) + tg];
        }
        #pragma unroll
        for (int off = 32; off > 0; off >>= 1) g += __shfl_down(g, off, 64);
        if (lane == 0) atomicAdd(&accum[1], g);
    }

    // ---------------- forward recursion ----------------
    __shared__ float csum[4][64];

    int rows[7];
    #pragma unroll
    for (int k = 0; k < 7; ++k) rows[k] = wave + 8 * k;   // rows[6] may be >= 50 (masked)

    const int lanec = (lane < K_TAGS) ? lane : (K_TAGS - 1);  // clamp keeps loads in-bounds

    // Issue this wave's row elements for timestep t (clamped) into dst registers.
    auto issue = [&](float (&dst)[7], int t) {
        int tc = (t < len) ? t : (len - 1);
        const float* s = sp + (size_t)tc * (K_TAGS * K_TAGS);
        #pragma unroll
        for (int k = 0; k < 7; ++k) {
            int i = rows[k];
            dst[k] = s[(i < K_TAGS ? i : 0) * K_TAGS + lanec];  // unconditional, clamped
        }
    };

    // beta0 (log2 domain): lane j holds bcur[j] = scores[b,0,START,j] * log2(e)
    float bcur = sp[START_TAG * K_TAGS + lanec] * LOG2E;
    float M = __shfl(bcur, 0, 64);

    // init: csum[0] = L0 (RD buffer of epoch 1), csum[1] = 0 (ADD buffer of epoch 1)
    if (wave == 0) {
        csum[0][lane] = (lane < K_TAGS) ? EXP2F(bcur - M) : 0.f;
    } else if (wave == 1) {
        csum[1][lane] = 0.f;
    }

    // 4-deep register prefetch: step s -> set s%4
    float sA[7], sB[7], sC[7], sD[7];
    issue(sB, 1); issue(sC, 2); issue(sD, 3); issue(sA, 4);

    // P for step 1 (prologue pays the load latency once)
    float P[7];
    #pragma unroll
    for (int k = 0; k < 7; ++k) P[k] = EXP2F(sB[k] * LOG2E);

    LDS_BARRIER();  // csum init visible; prefetch stays in flight

    // Epoch e (= timestep t): ADD=e%4, RD=(e+3)%4, ZR=(e+1)%4.
    // scExp = set holding step e+1's scores; scIssue = set to refill with step e+4.
    auto epoch = [&](float (&scIssue)[7], float (&scExp)[7], int e,
                     int ADD, int RD, int ZR) {
        float L  = csum[RD][lane];                 // merged L_{e-1}[lane]
        float L0 = __shfl(L, 0, 64);
        int   ei = (__float_as_int(L0) >> 23) & 0xFF;          // biased exponent
        float scale = __int_as_float((254 - ei) << 23);        // 2^-(ei-127)
        float Lb[7];
        #pragma unroll
        for (int k = 0; k < 7; ++k) {
            int i = rows[k];
            float v = __shfl(L, (i < K_TAGS) ? i : 0, 64);
            Lb[k] = (i < K_TAGS) ? v : 0.f;
        }
        float m0 = P[0] * Lb[0], m1 = P[1] * Lb[1], m2 = P[2] * Lb[2],
              m3 = P[3] * Lb[3], m4 = P[4] * Lb[4], m5 = P[5] * Lb[5],
              m6 = P[6] * Lb[6];
        float a = (((m0 + m1) + (m2 + m3)) + ((m4 + m5) + m6)) * scale;
        atomicAdd(&csum[ADD][lane], a);            // ds_add_f32 partial merge
        if (wave == 0) csum[ZR][lane] = 0.f;       // prep buffer for epoch e+1
        M += (float)(ei - 127);
        #pragma unroll
        for (int k = 0; k < 7; ++k) P[k] = EXP2F(scExp[k] * LOG2E);  // step e+1
        issue(scIssue, e + 4);                     // refill, 4 steps ahead
        LDS_BARRIER();
    };

    int t = 1;
    while (t < len) {
        epoch(sB, sC, t, 1, 0, 2); if (++t >= len) break;   // e%4==1
        epoch(sC, sD, t, 2, 1, 3); if (++t >= len) break;   // e%4==2
        epoch(sD, sA, t, 3, 2, 0); if (++t >= len) break;   // e%4==3
        epoch(sA, sB, t, 0, 3, 1); ++t;                     // e%4==0
    }

    float beta_end_log2;
    if (len >= 2) {
        beta_end_log2 = M + LOG2F(csum[(len - 1) & 3][lane]);
    } else {
        beta_end_log2 = bcur;
    }
    if (tid == END_TAG)                        // wave 0, lane 49 = beta_final[END_TAG]
        atomicAdd(&accum[0], beta_end_log2 * LN2);
}

__global__ void finalize_kernel(const float* __restrict__ accum,
                                float* __restrict__ out, float invB)
{
    out[0] = (accum[0] - accum[1]) * invB;
}

extern "C" void kernel_launch(void* const* d_in, const int* in_sizes, int n_in,
                              void* d_out, int out_size, void* d_ws, size_t ws_size,
                              hipStream_t stream)
{
    const float* scores  = (const float*)d_in[0];
    const int*   targets = (const int*)d_in[1];
    const int*   lengths = (const int*)d_in[2];
    const int B = in_sizes[2];

    float* accum = (float*)d_ws;
    hipMemsetAsync(accum, 0, 2 * sizeof(float), stream);
    crf_fwd_kernel<<<B, 512, 0, stream>>>(scores, targets, lengths, accum);
    finalize_kernel<<<1, 1, 0, stream>>>(accum, (float*)d_out, 1.0f / (float)B);
}